// Round 6
// baseline (253.462 us; speedup 1.0000x reference)
//
#include <hip/hip_runtime.h>
#include <math.h>

// Problem constants (fixed by reference: enc (32,64,64,64) fp32, embed (512,64) fp32)
#define DQ 64
#define KQ 512
#define NVEC 131072
#define QOUT_SIZE (NVEC * DQ)              // 8388608
#define LOSS_OFF QOUT_SIZE
#define IDX_OFF (QOUT_SIZE + 1)

#define VPB 64                             // vectors per block (4 waves x 16 rows)
#define NBLK (NVEC / VPB)                  // 2048 blocks
#define TIE_THR 0.01f                      // exact rescan when top-2 gap below this (err bound ~3e-4)

typedef __attribute__((ext_vector_type(8))) short short8;          // 8 bf16 = 1 MFMA A/B frag
typedef __attribute__((ext_vector_type(4))) float f32x4;           // MFMA C/D frag
typedef __attribute__((ext_vector_type(4))) unsigned short ushort4v;

static __device__ __forceinline__ unsigned short f2bf(float f) {   // RNE fp32->bf16
    unsigned u = __float_as_uint(f);
    u += 0x7fff + ((u >> 16) & 1);
    return (unsigned short)(u >> 16);
}
static __device__ __forceinline__ float bf2f(unsigned short h) {
    return __uint_as_float(((unsigned)h) << 16);
}

// Init: zero loss slot, precompute e_sq[k] AND the hi/lo bf16 split codebook
// into workspace (done ONCE here instead of per-block in R5 -> kills ~500
// VALU/thread of redundant conversion in the hot kernel).
__global__ void vq_init_kernel(const float* __restrict__ embed,
                               unsigned short* __restrict__ ehi,
                               unsigned short* __restrict__ elo,
                               float* __restrict__ esq,
                               float* __restrict__ out) {
    int k = blockIdx.x * blockDim.x + threadIdx.x;
    if (k == 0) out[LOSS_OFF] = 0.0f;
    if (k < KQ) {
        const float4* e4 = (const float4*)(embed + (size_t)k * DQ);
        float s = 0.f;
#pragma unroll
        for (int j = 0; j < 16; j++) {
            float4 a = e4[j];
            s = fmaf(a.x, a.x, s); s = fmaf(a.y, a.y, s);
            s = fmaf(a.z, a.z, s); s = fmaf(a.w, a.w, s);
            unsigned short h0 = f2bf(a.x), h1 = f2bf(a.y), h2 = f2bf(a.z), h3 = f2bf(a.w);
            ushort4v hv = { h0, h1, h2, h3 };
            ushort4v lv = { f2bf(a.x - bf2f(h0)), f2bf(a.y - bf2f(h1)),
                            f2bf(a.z - bf2f(h2)), f2bf(a.w - bf2f(h3)) };
            *(ushort4v*)(ehi + (size_t)k * DQ + j * 4) = hv;
            *(ushort4v*)(elo + (size_t)k * DQ + j * 4) = lv;
        }
        esq[k] = s;
    }
}

// One wave = 16 rows x 512 codes. B-fragments come straight from the
// precomputed global hi/lo codebook (L2-resident, no LDS staging, no
// barriers in the k-loop). Argmin per row: branchless (m1, m2, i1) via
// v_min/v_max/cndmask; x_sq dropped (row-constant -> argmin & gap invariant).
// Near-ties: wave-parallel exact fp64 rescan over ALL 512 codes.
// R3 lesson: register arrays only ever indexed by unrolled constants.
__global__ __launch_bounds__(256, 4) void vq_mfma_kernel(const float* __restrict__ enc,
                                                         const float* __restrict__ embed,
                                                         const unsigned short* __restrict__ ehi,
                                                         const unsigned short* __restrict__ elo,
                                                         const float* __restrict__ esq,
                                                         float* __restrict__ out) {
    __shared__ float esq_s[KQ];      // 2 KB
    __shared__ int bidx_s[VPB];
    __shared__ int flag_s[VPB];
    __shared__ float red[4];

    const int tid = threadIdx.x;
    const int lane = tid & 63;
    const int w = tid >> 6;            // wave 0..3
    const int l15 = lane & 15;
    const int l4 = lane >> 4;          // 0..3
    const int vb = blockIdx.x * VPB + w * 16;

    esq_s[tid] = esq[tid];
    esq_s[tid + 256] = esq[tid + 256];

    // A fragments: row m = l15, k-chunk l4*8 (khalf0) and 32+l4*8 (khalf1).
    const int arow = vb + l15;
    const float4* xa = (const float4*)(enc + (size_t)arow * DQ + l4 * 8);
    const float4* xb = (const float4*)(enc + (size_t)arow * DQ + 32 + l4 * 8);
    float4 x0 = xa[0], x1 = xa[1];
    float4 x2 = xb[0], x3 = xb[1];

    short8 ah0, al0, ah1, al1;
#define CVT(DH, DL, I, V) { unsigned short _h = f2bf(V); DH[I] = (short)_h; DL[I] = (short)f2bf((V) - bf2f(_h)); }
    CVT(ah0, al0, 0, x0.x) CVT(ah0, al0, 1, x0.y) CVT(ah0, al0, 2, x0.z) CVT(ah0, al0, 3, x0.w)
    CVT(ah0, al0, 4, x1.x) CVT(ah0, al0, 5, x1.y) CVT(ah0, al0, 6, x1.z) CVT(ah0, al0, 7, x1.w)
    CVT(ah1, al1, 0, x2.x) CVT(ah1, al1, 1, x2.y) CVT(ah1, al1, 2, x2.z) CVT(ah1, al1, 3, x2.w)
    CVT(ah1, al1, 4, x3.x) CVT(ah1, al1, 5, x3.y) CVT(ah1, al1, 6, x3.z) CVT(ah1, al1, 7, x3.w)

    __syncthreads();   // esq_s ready

    float m1[4], m2[4];
    int i1[4];
#pragma unroll
    for (int r = 0; r < 4; r++) { m1[r] = 3.4e38f; m2[r] = 3.4e38f; i1[r] = 0; }

    // B-frag base: code row = cb + l15, k-chunk l4*8 (+32).
    const unsigned short* ph = ehi + (size_t)l15 * DQ + l4 * 8;
    const unsigned short* pl = elo + (size_t)l15 * DQ + l4 * 8;

#pragma unroll 2
    for (int s = 0; s < 32; s++) {
        const int cb = s * 16;
        short8 bh0 = *(const short8*)(ph + cb * DQ);
        short8 bh1 = *(const short8*)(ph + cb * DQ + 32);
        short8 bl0 = *(const short8*)(pl + cb * DQ);
        short8 bl1 = *(const short8*)(pl + cb * DQ + 32);
        f32x4 acc = {0.f, 0.f, 0.f, 0.f};
        acc = __builtin_amdgcn_mfma_f32_16x16x32_bf16(ah0, bh0, acc, 0, 0, 0);
        acc = __builtin_amdgcn_mfma_f32_16x16x32_bf16(ah1, bh1, acc, 0, 0, 0);
        acc = __builtin_amdgcn_mfma_f32_16x16x32_bf16(al0, bh0, acc, 0, 0, 0);
        acc = __builtin_amdgcn_mfma_f32_16x16x32_bf16(al1, bh1, acc, 0, 0, 0);
        acc = __builtin_amdgcn_mfma_f32_16x16x32_bf16(ah0, bl0, acc, 0, 0, 0);
        acc = __builtin_amdgcn_mfma_f32_16x16x32_bf16(ah1, bl1, acc, 0, 0, 0);
        // xl*el term dropped: |err| <~ 2e-4 << TIE_THR

        const float ev = esq_s[cb + l15];
        const int code = cb + l15;                 // C/D col = lane&15
#pragma unroll
        for (int r = 0; r < 4; r++) {              // C/D row = l4*4 + r
            float v = fmaf(-2.0f, acc[r], ev);     // e_sq - 2*dot (x_sq dropped)
            bool lt = v < m1[r];
            i1[r] = lt ? code : i1[r];
            m2[r] = fminf(m2[r], fmaxf(m1[r], v));
            m1[r] = fminf(m1[r], v);
        }
    }

    // Cross-lane merge over the 16 cols (xor on lane&15 bits). Equal-value
    // collisions leave gap==0 -> flagged -> exact rescan resolves.
#pragma unroll
    for (int m = 1; m <= 8; m <<= 1) {
#pragma unroll
        for (int r = 0; r < 4; r++) {
            float o1 = __shfl_xor(m1[r], m);
            float o2 = __shfl_xor(m2[r], m);
            int oi = __shfl_xor(i1[r], m);
            float nm2 = fminf(fminf(m2[r], o2), fmaxf(m1[r], o1));
            bool lt = o1 < m1[r];
            i1[r] = lt ? oi : i1[r];
            m1[r] = fminf(m1[r], o1);
            m2[r] = nm2;
        }
    }

    if (l15 == 0) {
#pragma unroll
        for (int r = 0; r < 4; r++) {
            const int row = l4 * 4 + r;
            bidx_s[w * 16 + row] = i1[r];
            flag_s[w * 16 + row] = (m2[r] - m1[r] < TIE_THR) ? 1 : 0;
        }
    }
    __syncthreads();

    // Exact fp64 rescan of flagged rows (wave-uniform branch; rare ~1%).
    // All 64 lanes cooperate: 8 codes/lane, packed (d2bits|code) u64 min.
    for (int row = 0; row < 16; row++) {
        if (flag_s[w * 16 + row]) {
            const int v = vb + row;
            const float4* xe = (const float4*)(enc + (size_t)v * DQ);
            unsigned long long best = ~0ULL;
            for (int q = 0; q < 8; q++) {
                const int c = lane * 8 + q;
                const float4* ee = (const float4*)(embed + (size_t)c * DQ);
                double a = 0.0;
                for (int j = 0; j < 16; j++) {          // global ptrs: runtime j fine
                    float4 xx = xe[j], ez = ee[j];
                    double d0 = (double)xx.x - (double)ez.x; a = fma(d0, d0, a);
                    double d1 = (double)xx.y - (double)ez.y; a = fma(d1, d1, a);
                    double d2 = (double)xx.z - (double)ez.z; a = fma(d2, d2, a);
                    double d3 = (double)xx.w - (double)ez.w; a = fma(d3, d3, a);
                }
                unsigned long long p =
                    (((unsigned long long)__double_as_longlong(a)) & ~511ULL) | (unsigned)c;
                best = (p < best) ? p : best;
            }
#pragma unroll
            for (int mm = 1; mm < 64; mm <<= 1) {
                unsigned long long ob = (unsigned long long)__shfl_xor((long long)best, mm);
                best = (ob < best) ? ob : best;
            }
            if (lane == 0) bidx_s[w * 16 + row] = (int)(best & 511ULL);
        }
    }
    __syncthreads();

    // Epilogue: lane handles row l15 of its wave, chunks l4*8 and 32+l4*8.
    const int myv = vb + l15;
    const int qb = bidx_s[w * 16 + l15];
    const float4* qa = (const float4*)(embed + (size_t)qb * DQ + l4 * 8);
    const float4* qc = (const float4*)(embed + (size_t)qb * DQ + 32 + l4 * 8);
    float4 q0 = qa[0], q1 = qa[1], q2 = qc[0], q3 = qc[1];
    float4* oa = (float4*)(out + (size_t)myv * DQ + l4 * 8);
    float4* oc = (float4*)(out + (size_t)myv * DQ + 32 + l4 * 8);
    oa[0] = q0; oa[1] = q1;
    oc[0] = q2; oc[1] = q3;
    if (l4 == 0) out[IDX_OFF + myv] = (float)qb;

    float ls = 0.f, d;
    d = q0.x - x0.x; ls = fmaf(d, d, ls); d = q0.y - x0.y; ls = fmaf(d, d, ls);
    d = q0.z - x0.z; ls = fmaf(d, d, ls); d = q0.w - x0.w; ls = fmaf(d, d, ls);
    d = q1.x - x1.x; ls = fmaf(d, d, ls); d = q1.y - x1.y; ls = fmaf(d, d, ls);
    d = q1.z - x1.z; ls = fmaf(d, d, ls); d = q1.w - x1.w; ls = fmaf(d, d, ls);
    d = q2.x - x2.x; ls = fmaf(d, d, ls); d = q2.y - x2.y; ls = fmaf(d, d, ls);
    d = q2.z - x2.z; ls = fmaf(d, d, ls); d = q2.w - x2.w; ls = fmaf(d, d, ls);
    d = q3.x - x3.x; ls = fmaf(d, d, ls); d = q3.y - x3.y; ls = fmaf(d, d, ls);
    d = q3.z - x3.z; ls = fmaf(d, d, ls); d = q3.w - x3.w; ls = fmaf(d, d, ls);

#pragma unroll
    for (int off = 32; off > 0; off >>= 1) ls += __shfl_down(ls, off);
    if (lane == 0) red[w] = ls;
    __syncthreads();
    if (tid == 0) {
        float s = (red[0] + red[1]) + (red[2] + red[3]);
        atomicAdd(out + LOSS_OFF, s * (2.0f / (float)QOUT_SIZE));
    }
}

extern "C" void kernel_launch(void* const* d_in, const int* in_sizes, int n_in,
                              void* d_out, int out_size, void* d_ws, size_t ws_size,
                              hipStream_t stream) {
    const float* enc = (const float*)d_in[0];
    const float* embed = (const float*)d_in[1];
    float* out = (float*)d_out;
    // ws layout: ehi[512*64] u16 | elo[512*64] u16 | esq[512] f32  (~130 KB)
    unsigned short* ehi = (unsigned short*)d_ws;
    unsigned short* elo = ehi + KQ * DQ;
    float* esq = (float*)(elo + KQ * DQ);

    hipLaunchKernelGGL(vq_init_kernel, dim3(2), dim3(256), 0, stream,
                       embed, ehi, elo, esq, out);
    hipLaunchKernelGGL(vq_mfma_kernel, dim3(NBLK), dim3(256), 0, stream,
                       enc, embed, ehi, elo, esq, out);
}

// Round 7
// 174.815 us; speedup vs baseline: 1.4499x; 1.4499x over previous
//
#include <hip/hip_runtime.h>
#include <math.h>

// Problem constants (fixed by reference: enc (32,64,64,64) fp32, embed (512,64) fp32)
#define DQ 64
#define KQ 512
#define NVEC 131072
#define QOUT_SIZE (NVEC * DQ)              // 8388608
#define LOSS_OFF QOUT_SIZE
#define IDX_OFF (QOUT_SIZE + 1)

#define RPW 64                             // rows per wave (4 MFMA A-tiles)
#define VPB (RPW * 4)                      // 256 rows per block (4 waves)
#define NBLK (NVEC / VPB)                  // 512 blocks
#define TIE_THR 0.01f                      // exact rescan when top-2 gap below this (err bound ~3e-4)

typedef __attribute__((ext_vector_type(8))) short short8;          // 8 bf16 = 1 MFMA A/B frag
typedef __attribute__((ext_vector_type(4))) float f32x4;           // MFMA C/D frag
typedef __attribute__((ext_vector_type(4))) unsigned short ushort4v;

static __device__ __forceinline__ unsigned short f2bf(float f) {   // RNE fp32->bf16
    unsigned u = __float_as_uint(f);
    u += 0x7fff + ((u >> 16) & 1);
    return (unsigned short)(u >> 16);
}
static __device__ __forceinline__ float bf2f(unsigned short h) {
    return __uint_as_float(((unsigned)h) << 16);
}
static __device__ __forceinline__ void cvt8(float4 a, float4 b, short8& hi, short8& lo) {
#define C1(I, V) { unsigned short _h = f2bf(V); hi[I] = (short)_h; lo[I] = (short)f2bf((V) - bf2f(_h)); }
    C1(0, a.x) C1(1, a.y) C1(2, a.z) C1(3, a.w)
    C1(4, b.x) C1(5, b.y) C1(6, b.z) C1(7, b.w)
#undef C1
}

// Init: zero loss slot, precompute e_sq[k] and the hi/lo bf16 codebook (once).
__global__ void vq_init_kernel(const float* __restrict__ embed,
                               unsigned short* __restrict__ ehi,
                               unsigned short* __restrict__ elo,
                               float* __restrict__ esq,
                               float* __restrict__ out) {
    int k = blockIdx.x * blockDim.x + threadIdx.x;
    if (k == 0) out[LOSS_OFF] = 0.0f;
    if (k < KQ) {
        const float4* e4 = (const float4*)(embed + (size_t)k * DQ);
        float s = 0.f;
#pragma unroll
        for (int j = 0; j < 16; j++) {
            float4 a = e4[j];
            s = fmaf(a.x, a.x, s); s = fmaf(a.y, a.y, s);
            s = fmaf(a.z, a.z, s); s = fmaf(a.w, a.w, s);
            unsigned short h0 = f2bf(a.x), h1 = f2bf(a.y), h2 = f2bf(a.z), h3 = f2bf(a.w);
            ushort4v hv = { h0, h1, h2, h3 };
            ushort4v lv = { f2bf(a.x - bf2f(h0)), f2bf(a.y - bf2f(h1)),
                            f2bf(a.z - bf2f(h2)), f2bf(a.w - bf2f(h3)) };
            *(ushort4v*)(ehi + (size_t)k * DQ + j * 4) = hv;
            *(ushort4v*)(elo + (size_t)k * DQ + j * 4) = lv;
        }
        esq[k] = s;
    }
}

// One wave = 64 rows (4 A-tiles) x 512 codes. B streams from the precomputed
// global hi/lo codebook with an explicit 1-tile double-buffer prefetch; each
// 4KB B-tile now feeds 24 MFMAs + cascade (R6 was 6 -> pure latency-bound).
// Branchless (m1,m2,i1) argmin; near-ties -> wave-parallel exact fp64 rescan.
// R3 lesson: register arrays only indexed by fully-unrolled constants.
__global__ __launch_bounds__(256, 2) void vq_mfma_kernel(const float* __restrict__ enc,
                                                         const float* __restrict__ embed,
                                                         const unsigned short* __restrict__ ehi,
                                                         const unsigned short* __restrict__ elo,
                                                         const float* __restrict__ esq,
                                                         float* __restrict__ out) {
    __shared__ float esq_s[KQ];      // 2 KB
    __shared__ int bidx_s[VPB];
    __shared__ int flag_s[VPB];
    __shared__ float red[4];

    const int tid = threadIdx.x;
    const int lane = tid & 63;
    const int w = tid >> 6;            // wave 0..3
    const int l15 = lane & 15;
    const int l4 = lane >> 4;          // 0..3
    const int vb = blockIdx.x * VPB + w * RPW;

    esq_s[tid] = esq[tid];
    esq_s[tid + 256] = esq[tid + 256];

    // A fragments for 4 tiles: row m = l15 (+a*16), k-chunks l4*8 and 32+l4*8.
    short8 ahA[4], alA[4], ahB[4], alB[4];
#pragma unroll
    for (int a = 0; a < 4; a++) {
        const float* base = enc + (size_t)(vb + a * 16 + l15) * DQ + l4 * 8;
        const float4* p0 = (const float4*)base;
        const float4* p1 = (const float4*)(base + 32);
        cvt8(p0[0], p0[1], ahA[a], alA[a]);
        cvt8(p1[0], p1[1], ahB[a], alB[a]);
    }

    __syncthreads();   // esq_s ready

    float m1[16], m2[16];
    int i1[16];
#pragma unroll
    for (int r = 0; r < 16; r++) { m1[r] = 3.4e38f; m2[r] = 3.4e38f; i1[r] = 0; }

    // B-frag base: code row = cb + l15, k-chunk l4*8 (+32).
    const unsigned short* ph = ehi + (size_t)l15 * DQ + l4 * 8;
    const unsigned short* pl = elo + (size_t)l15 * DQ + l4 * 8;

#define LDB(H0, H1, L0, L1, S) { \
    const int _o = (S) * 16 * DQ; \
    H0 = *(const short8*)(ph + _o);      H1 = *(const short8*)(ph + _o + 32); \
    L0 = *(const short8*)(pl + _o);      L1 = *(const short8*)(pl + _o + 32); }

#define BODY(S, BH0, BH1, BL0, BL1) { \
    const float ev = esq_s[(S) * 16 + l15]; \
    const int code = (S) * 16 + l15; \
    _Pragma("unroll") \
    for (int a = 0; a < 4; a++) { \
        f32x4 acc = {0.f, 0.f, 0.f, 0.f}; \
        acc = __builtin_amdgcn_mfma_f32_16x16x32_bf16(ahA[a], BH0, acc, 0, 0, 0); \
        acc = __builtin_amdgcn_mfma_f32_16x16x32_bf16(ahB[a], BH1, acc, 0, 0, 0); \
        acc = __builtin_amdgcn_mfma_f32_16x16x32_bf16(alA[a], BH0, acc, 0, 0, 0); \
        acc = __builtin_amdgcn_mfma_f32_16x16x32_bf16(alB[a], BH1, acc, 0, 0, 0); \
        acc = __builtin_amdgcn_mfma_f32_16x16x32_bf16(ahA[a], BL0, acc, 0, 0, 0); \
        acc = __builtin_amdgcn_mfma_f32_16x16x32_bf16(ahB[a], BL1, acc, 0, 0, 0); \
        _Pragma("unroll") \
        for (int r = 0; r < 4; r++) { \
            float v = fmaf(-2.0f, acc[r], ev); \
            bool lt = v < m1[a * 4 + r]; \
            i1[a * 4 + r] = lt ? code : i1[a * 4 + r]; \
            m2[a * 4 + r] = fminf(m2[a * 4 + r], fmaxf(m1[a * 4 + r], v)); \
            m1[a * 4 + r] = fminf(m1[a * 4 + r], v); \
        } \
    } }

    short8 b0h0, b0h1, b0l0, b0l1, b1h0, b1h1, b1l0, b1l1;
    LDB(b0h0, b0h1, b0l0, b0l1, 0)
    for (int s = 0; s < 32; s += 2) {
        LDB(b1h0, b1h1, b1l0, b1l1, s + 1)           // prefetch odd tile
        BODY(s, b0h0, b0h1, b0l0, b0l1)
        if (s + 2 < 32) LDB(b0h0, b0h1, b0l0, b0l1, s + 2)   // prefetch next even
        BODY(s + 1, b1h0, b1h1, b1l0, b1l1)
    }
#undef LDB
#undef BODY

    // Cross-lane merge over the 16 cols (xor on lane&15 bits).
#pragma unroll
    for (int m = 1; m <= 8; m <<= 1) {
#pragma unroll
        for (int r = 0; r < 16; r++) {
            float o1 = __shfl_xor(m1[r], m);
            float o2 = __shfl_xor(m2[r], m);
            int oi = __shfl_xor(i1[r], m);
            float nm2 = fminf(fminf(m2[r], o2), fmaxf(m1[r], o1));
            bool lt = o1 < m1[r];
            i1[r] = lt ? oi : i1[r];
            m1[r] = fminf(m1[r], o1);
            m2[r] = nm2;
        }
    }

    if (l15 == 0) {
#pragma unroll
        for (int a = 0; a < 4; a++)
#pragma unroll
            for (int r = 0; r < 4; r++) {
                const int row = a * 16 + l4 * 4 + r;
                bidx_s[w * RPW + row] = i1[a * 4 + r];
                flag_s[w * RPW + row] = (m2[a * 4 + r] - m1[a * 4 + r] < TIE_THR) ? 1 : 0;
            }
    }
    __syncthreads();

    // Exact fp64 rescan of flagged rows (wave-uniform branch; rare ~1%).
    for (int row = 0; row < RPW; row++) {
        if (flag_s[w * RPW + row]) {
            const int v = vb + row;
            const float4* xe = (const float4*)(enc + (size_t)v * DQ);
            unsigned long long best = ~0ULL;
            for (int q = 0; q < 8; q++) {
                const int c = lane * 8 + q;
                const float4* ee = (const float4*)(embed + (size_t)c * DQ);
                double a = 0.0;
                for (int j = 0; j < 16; j++) {          // global ptrs: runtime j fine
                    float4 xx = xe[j], ez = ee[j];
                    double d0 = (double)xx.x - (double)ez.x; a = fma(d0, d0, a);
                    double d1 = (double)xx.y - (double)ez.y; a = fma(d1, d1, a);
                    double d2 = (double)xx.z - (double)ez.z; a = fma(d2, d2, a);
                    double d3 = (double)xx.w - (double)ez.w; a = fma(d3, d3, a);
                }
                unsigned long long p =
                    (((unsigned long long)__double_as_longlong(a)) & ~511ULL) | (unsigned)c;
                best = (p < best) ? p : best;
            }
#pragma unroll
            for (int mm = 1; mm < 64; mm <<= 1) {
                unsigned long long ob = (unsigned long long)__shfl_xor((long long)best, mm);
                best = (ob < best) ? ob : best;
            }
            if (lane == 0) bidx_s[w * RPW + row] = (int)(best & 511ULL);
        }
    }
    __syncthreads();

    // Epilogue: per tile a, lane handles row a*16+l15, chunks l4*8 and 32+l4*8.
    // x is recomputed from the hi/lo frags (≈1e-5 rel err; loss-only).
    float ls = 0.f;
#pragma unroll
    for (int a = 0; a < 4; a++) {
        const int myv = vb + a * 16 + l15;
        const int qb = bidx_s[w * RPW + a * 16 + l15];
        const float* qbase = embed + (size_t)qb * DQ + l4 * 8;
        const float4* qa = (const float4*)qbase;
        const float4* qc = (const float4*)(qbase + 32);
        float4 q0 = qa[0], q1 = qa[1], q2 = qc[0], q3 = qc[1];
        float* obase = out + (size_t)myv * DQ + l4 * 8;
        ((float4*)obase)[0] = q0; ((float4*)obase)[1] = q1;
        ((float4*)(obase + 32))[0] = q2; ((float4*)(obase + 32))[1] = q3;
        if (l4 == 0) out[IDX_OFF + myv] = (float)qb;

        float d;
        d = q0.x - (bf2f(ahA[a][0]) + bf2f(alA[a][0])); ls = fmaf(d, d, ls);
        d = q0.y - (bf2f(ahA[a][1]) + bf2f(alA[a][1])); ls = fmaf(d, d, ls);
        d = q0.z - (bf2f(ahA[a][2]) + bf2f(alA[a][2])); ls = fmaf(d, d, ls);
        d = q0.w - (bf2f(ahA[a][3]) + bf2f(alA[a][3])); ls = fmaf(d, d, ls);
        d = q1.x - (bf2f(ahA[a][4]) + bf2f(alA[a][4])); ls = fmaf(d, d, ls);
        d = q1.y - (bf2f(ahA[a][5]) + bf2f(alA[a][5])); ls = fmaf(d, d, ls);
        d = q1.z - (bf2f(ahA[a][6]) + bf2f(alA[a][6])); ls = fmaf(d, d, ls);
        d = q1.w - (bf2f(ahA[a][7]) + bf2f(alA[a][7])); ls = fmaf(d, d, ls);
        d = q2.x - (bf2f(ahB[a][0]) + bf2f(alB[a][0])); ls = fmaf(d, d, ls);
        d = q2.y - (bf2f(ahB[a][1]) + bf2f(alB[a][1])); ls = fmaf(d, d, ls);
        d = q2.z - (bf2f(ahB[a][2]) + bf2f(alB[a][2])); ls = fmaf(d, d, ls);
        d = q2.w - (bf2f(ahB[a][3]) + bf2f(alB[a][3])); ls = fmaf(d, d, ls);
        d = q3.x - (bf2f(ahB[a][4]) + bf2f(alB[a][4])); ls = fmaf(d, d, ls);
        d = q3.y - (bf2f(ahB[a][5]) + bf2f(alB[a][5])); ls = fmaf(d, d, ls);
        d = q3.z - (bf2f(ahB[a][6]) + bf2f(alB[a][6])); ls = fmaf(d, d, ls);
        d = q3.w - (bf2f(ahB[a][7]) + bf2f(alB[a][7])); ls = fmaf(d, d, ls);
    }

#pragma unroll
    for (int off = 32; off > 0; off >>= 1) ls += __shfl_down(ls, off);
    if (lane == 0) red[w] = ls;
    __syncthreads();
    if (tid == 0) {
        float s = (red[0] + red[1]) + (red[2] + red[3]);
        atomicAdd(out + LOSS_OFF, s * (2.0f / (float)QOUT_SIZE));
    }
}

extern "C" void kernel_launch(void* const* d_in, const int* in_sizes, int n_in,
                              void* d_out, int out_size, void* d_ws, size_t ws_size,
                              hipStream_t stream) {
    const float* enc = (const float*)d_in[0];
    const float* embed = (const float*)d_in[1];
    float* out = (float*)d_out;
    // ws layout: ehi[512*64] u16 | elo[512*64] u16 | esq[512] f32  (~130 KB)
    unsigned short* ehi = (unsigned short*)d_ws;
    unsigned short* elo = ehi + KQ * DQ;
    float* esq = (float*)(elo + KQ * DQ);

    hipLaunchKernelGGL(vq_init_kernel, dim3(8), dim3(64), 0, stream,
                       embed, ehi, elo, esq, out);
    hipLaunchKernelGGL(vq_mfma_kernel, dim3(NBLK), dim3(256), 0, stream,
                       enc, embed, ehi, elo, esq, out);
}